// Round 6
// baseline (118.121 us; speedup 1.0000x reference)
//
#include <hip/hip_runtime.h>
#include <math.h>

#define A_NUM 8732
#define O_NUM 32
#define NEGPOS 3
#define NTHR 256
#define NWAVE (NTHR / 64)
#define ASPLIT 16
#define APB (A_NUM / ASPLIT + 1)              // 546 (546*16 = 8736 >= 8732)
#define JMAX ((APB + NTHR - 1) / NTHR)        // 3
#define LOGEPS_F (-27.631021115928547f)       // log(1e-12)

__device__ __forceinline__ float rfl(float x) {
    return __int_as_float(__builtin_amdgcn_readfirstlane(__float_as_int(x)));
}

// top-18 bits of IoU as a uint (IoU >= 0 so uint order == float order)
__device__ __forceinline__ unsigned int iou_hi(float tx1, float ty1, float tx2, float ty2, float ta,
                                               float px1, float py1, float px2, float py2, float ap) {
    float w = __saturatef(fminf(tx2, px2) - fmaxf(tx1, px1));
    float h = __saturatef(fminf(ty2, py2) - fmaxf(ty1, py1));
    float inter = w * h;
    float uni = (ta + ap) - inter;
    float iou = inter * __builtin_amdgcn_rcpf(uni);
    return __float_as_uint(iou) & 0xFFFFC000u;
}

__device__ __forceinline__ float sl1_sum(float4 t, float4 pr, float4 ld) {
    float gx = ((t.x + t.z) * 0.5f - pr.x) / (0.1f * pr.z);
    float gy = ((t.y + t.w) * 0.5f - pr.y) / (0.1f * pr.w);
    float gw = logf((t.z - t.x) / pr.z) / 0.2f;
    float gh = logf((t.w - t.y) / pr.w) / 0.2f;
    float d0 = ld.x - gx, d1 = ld.y - gy, d2 = ld.z - gw, d3 = ld.w - gh;
    float a0 = fabsf(d0), a1 = fabsf(d1), a2 = fabsf(d2), a3 = fabsf(d3);
    float s0 = (a0 < 1.0f) ? 0.5f * d0 * d0 : a0 - 0.5f;
    float s1 = (a1 < 1.0f) ? 0.5f * d1 * d1 : a1 - 0.5f;
    float s2 = (a2 < 1.0f) ? 0.5f * d2 * d2 : a2 - 0.5f;
    float s3 = (a3 < 1.0f) ? 0.5f * d3 * d3 : a3 - 0.5f;
    return s0 + s1 + s2 + s3;
}

__device__ __forceinline__ float bce_pos(int pred, float tgt) {
    float logp   = (pred == 0) ? LOGEPS_F : 0.0f;
    float log1mp = (pred == 1) ? LOGEPS_F : 0.0f;
    return -(tgt * logp + (1.0f - tgt) * log1mp);
}

// K1: grid = BF*ASPLIT blocks of 256 threads; block handles APB anchors of one frame.
// Per-truth best-anchor keys merged into per-frame table via atomicMax.
__global__ __launch_bounds__(NTHR) void mfbl_k1(
    const float* __restrict__ loc_data, const float* __restrict__ conf_data,
    const float* __restrict__ anchors, const float* __restrict__ targets,
    unsigned int* __restrict__ g_tred, float4* __restrict__ g_part)
{
    const int bid = blockIdx.x;
    const int frame = bid >> 4;
    const int split = bid & 15;
    const int a_lo = split * APB;
    const int a_hi = min(a_lo + APB, A_NUM);
    const int tid = threadIdx.x;
    const int lane = tid & 63, wid = tid >> 6;

    __shared__ float4 s_tc[O_NUM];
    __shared__ float s_ta[O_NUM], s_lab[O_NUM];
    __shared__ unsigned int s_tred[O_NUM][NWAVE];
    __shared__ float s_r[4][NWAVE];

    if (tid < O_NUM) {
        const float* t = targets + ((size_t)frame * O_NUM + tid) * 5;
        float x1 = t[0], y1 = t[1], x2 = t[2], y2 = t[3];
        s_tc[tid] = make_float4(x1, y1, x2, y2);
        s_ta[tid] = (x2 - x1) * (y2 - y1);
        s_lab[tid] = t[4];
    }
    __syncthreads();

    // anchors in registers (clamped duplicates for tail lanes; their per-truth
    // keys can never win because aT is strictly smaller than the real copy's)
    float px1[JMAX], py1[JMAX], px2[JMAX], py2[JMAX], ap[JMAX];
    unsigned int bestA[JMAX], aT[JMAX];
#pragma unroll
    for (int j = 0; j < JMAX; ++j) {
        int a = a_lo + tid + j * NTHR;
        int ac = min(a, a_hi - 1);
        float4 pr = *(const float4*)(anchors + (size_t)ac * 4);
        float hw = pr.z * 0.5f, hh = pr.w * 0.5f;
        px1[j] = pr.x - hw; py1[j] = pr.y - hh;
        px2[j] = pr.x + hw; py2[j] = pr.y + hh;
        ap[j] = (px2[j] - px1[j]) * (py2[j] - py1[j]);
        bestA[j] = 0u;
        aT[j] = 16383u - (unsigned int)a;
    }

    // 4 chunks of 8 truths, truths hoisted to SGPRs -> zero LDS in hot loop
#pragma unroll
    for (int c = 0; c < 4; ++c) {
        float tx1[8], ty1[8], tx2[8], ty2[8], tta[8];
        unsigned int tb8[8];
#pragma unroll
        for (int o8 = 0; o8 < 8; ++o8) {
            float4 t = s_tc[c * 8 + o8];
            tx1[o8] = rfl(t.x); ty1[o8] = rfl(t.y);
            tx2[o8] = rfl(t.z); ty2[o8] = rfl(t.w);
            tta[o8] = rfl(s_ta[c * 8 + o8]);
            tb8[o8] = 0u;
        }
#pragma unroll
        for (int o8 = 0; o8 < 8; ++o8) {
            const unsigned int oc = (unsigned int)(31 - (c * 8 + o8));
#pragma unroll
            for (int j = 0; j < JMAX; ++j) {
                unsigned int hi = iou_hi(tx1[o8], ty1[o8], tx2[o8], ty2[o8], tta[o8],
                                         px1[j], py1[j], px2[j], py2[j], ap[j]);
                bestA[j] = max(bestA[j], hi | oc);
                tb8[o8]  = max(tb8[o8], hi | aT[j]);
            }
        }
#pragma unroll
        for (int o8 = 0; o8 < 8; ++o8) {
            unsigned int k = tb8[o8];
            for (int s = 32; s > 0; s >>= 1)
                k = max(k, (unsigned int)__shfl_down((int)k, s));
            if (lane == 0) s_tred[c * 8 + o8][wid] = k;
        }
    }
    __syncthreads();
    if (tid < O_NUM) {
        unsigned int k = s_tred[tid][0];
        for (int w = 1; w < NWAVE; ++w) k = max(k, s_tred[tid][w]);
        atomicMax(&g_tred[(size_t)frame * O_NUM + tid], k);   // commutative -> deterministic
    }

    // fused pass 2: unforced contributions
    float l_sum = 0.0f, cpos = 0.0f, np_cnt = 0.0f, m_cnt = 0.0f;
#pragma unroll
    for (int j = 0; j < JMAX; ++j) {
        int a = a_lo + tid + j * NTHR;
        if (a < a_hi) {
            unsigned int k = bestA[j];
            int o = 31 - (int)(k & 31u);
            unsigned int hi = k & 0xFFFFC000u;
            const float2 cd = *(const float2*)(conf_data + ((size_t)frame * A_NUM + a) * 2);
            int pred = (cd.y > cd.x) ? 1 : 0;
            int cv = (hi >= 0x3F000000u) ? (int)s_lab[o] + 1 : 0;
            if (cv > 0) {
                np_cnt += 1.0f;
                float4 pr = *(const float4*)(anchors + (size_t)a * 4);
                float4 ld = *(const float4*)(loc_data + ((size_t)frame * A_NUM + a) * 4);
                l_sum += sl1_sum(s_tc[o], pr, ld);
                cpos += bce_pos(pred, (float)cv);
            } else {
                m_cnt += (float)pred;   // negative with lc > log2 <=> pred==1
            }
        }
    }
    for (int s = 32; s > 0; s >>= 1) {
        l_sum  += __shfl_down(l_sum, s);
        cpos   += __shfl_down(cpos, s);
        np_cnt += __shfl_down(np_cnt, s);
        m_cnt  += __shfl_down(m_cnt, s);
    }
    if (lane == 0) { s_r[0][wid] = l_sum; s_r[1][wid] = cpos; s_r[2][wid] = np_cnt; s_r[3][wid] = m_cnt; }
    __syncthreads();
    if (tid == 0) {
        float L = 0, C = 0, NP = 0, M = 0;
        for (int w = 0; w < NWAVE; ++w) { L += s_r[0][w]; C += s_r[1][w]; NP += s_r[2][w]; M += s_r[3][w]; }
        g_part[bid] = make_float4(L, C, NP, M);
    }
}

// K2: grid = BF blocks x 64 threads. Apply forced-match corrections
// (<=32 anchors/frame), finalize per-frame losses.
__global__ __launch_bounds__(64) void mfbl_k2(
    const float* __restrict__ loc_data, const float* __restrict__ conf_data,
    const float* __restrict__ anchors, const float* __restrict__ targets,
    const unsigned int* __restrict__ g_tred, const float4* __restrict__ g_part,
    float* __restrict__ ws_l, float* __restrict__ ws_c)
{
    const int frame = blockIdx.x;
    const int tid = threadIdx.x;

    __shared__ float4 s_tc[O_NUM];
    __shared__ float s_ta[O_NUM], s_lab[O_NUM];
    __shared__ int s_bp[O_NUM];

    if (tid < O_NUM) {
        const float* t = targets + ((size_t)frame * O_NUM + tid) * 5;
        float x1 = t[0], y1 = t[1], x2 = t[2], y2 = t[3];
        s_tc[tid] = make_float4(x1, y1, x2, y2);
        s_ta[tid] = (x2 - x1) * (y2 - y1);
        s_lab[tid] = t[4];
        unsigned int k = g_tred[(size_t)frame * O_NUM + tid];
        s_bp[tid] = 16383 - (int)(k & 16383u);
    }
    __syncthreads();

    float dL = 0.0f, dC = 0.0f, dNP = 0.0f, dM = 0.0f;
    if (tid < O_NUM) {
        int a = s_bp[tid];
        bool owner = true;                       // last truth writing this anchor wins
        for (int o2 = tid + 1; o2 < O_NUM; ++o2)
            if (s_bp[o2] == a) owner = false;
        if (owner) {
            float4 pr = *(const float4*)(anchors + (size_t)a * 4);
            float hw = pr.z * 0.5f, hh = pr.w * 0.5f;
            float px1 = pr.x - hw, py1 = pr.y - hh;
            float px2 = pr.x + hw, py2 = pr.y + hh;
            float apn = (px2 - px1) * (py2 - py1);
            unsigned int bk = 0u;                // recompute unforced best truth
            for (int o2 = 0; o2 < O_NUM; ++o2) {
                float4 t = s_tc[o2];
                unsigned int hi = iou_hi(t.x, t.y, t.z, t.w, s_ta[o2], px1, py1, px2, py2, apn);
                bk = max(bk, hi | (unsigned int)(31 - o2));
            }
            int old_o = 31 - (int)(bk & 31u);
            unsigned int old_hi = bk & 0xFFFFC000u;
            int old_cv = (old_hi >= 0x3F000000u) ? (int)s_lab[old_o] + 1 : 0;
            const float2 cd = *(const float2*)(conf_data + ((size_t)frame * A_NUM + a) * 2);
            int pred = (cd.y > cd.x) ? 1 : 0;
            float4 ld = *(const float4*)(loc_data + ((size_t)frame * A_NUM + a) * 4);
            int new_cv = (int)s_lab[tid] + 1;
            dL = sl1_sum(s_tc[tid], pr, ld);
            dC = bce_pos(pred, (float)new_cv);
            dNP = 1.0f;
            if (old_cv > 0) {
                dL -= sl1_sum(s_tc[old_o], pr, ld);
                dC -= bce_pos(pred, (float)old_cv);
                dNP -= 1.0f;
            } else {
                dM -= (float)pred;
            }
        }
    }
    for (int s = 32; s > 0; s >>= 1) {
        dL += __shfl_down(dL, s);
        dC += __shfl_down(dC, s);
        dNP += __shfl_down(dNP, s);
        dM += __shfl_down(dM, s);
    }
    if (tid == 0) {
        float L = 0, C = 0, NP = 0, M = 0;
        for (int s = 0; s < ASPLIT; ++s) {
            float4 p = g_part[frame * ASPLIT + s];
            L += p.x; C += p.y; NP += p.z; M += p.w;
        }
        L += dL; C += dC; NP += dNP; M += dM;
        int np = (int)NP, m = (int)M;
        int num_neg = min(NEGPOS * np, A_NUM - 1);
        int nsel = min(num_neg, m);
        ws_l[frame] = L;
        ws_c[frame] = C + 27.631021115928547f * (float)nsel;
    }
}

__global__ void mfbl_k3(const float* __restrict__ ws_l, const float* __restrict__ ws_c,
                        float* __restrict__ out, int n) {
    int tid = threadIdx.x;
    float a = (tid < n) ? ws_l[tid] : 0.0f;
    float b = (tid < n) ? ws_c[tid] : 0.0f;
    for (int s = 32; s > 0; s >>= 1) {
        a += __shfl_down(a, s);
        b += __shfl_down(b, s);
    }
    __shared__ float sa[4], sb[4];
    int lane = tid & 63, wid = tid >> 6;
    if (lane == 0) { sa[wid] = a; sb[wid] = b; }
    __syncthreads();
    if (tid == 0) {
        float A = 0.0f, B = 0.0f;
        for (int w = 0; w < 4; ++w) { A += sa[w]; B += sb[w]; }
        out[0] = A;
        out[1] = B;
    }
}

extern "C" void kernel_launch(void* const* d_in, const int* in_sizes, int n_in,
                              void* d_out, int out_size, void* d_ws, size_t ws_size,
                              hipStream_t stream) {
    const float* loc     = (const float*)d_in[0];
    const float* conf    = (const float*)d_in[1];
    const float* anchors = (const float*)d_in[2];
    const float* targets = (const float*)d_in[3];
    float* out = (float*)d_out;
    (void)ws_size;

    const int BF = in_sizes[3] / (O_NUM * 5);   // 256 frames
    const int NBLK = BF * ASPLIT;

    unsigned int* g_tred = (unsigned int*)d_ws;                                   // BF*32 u32
    float4* g_part = (float4*)((char*)d_ws + (size_t)BF * O_NUM * 4);             // NBLK float4
    float* ws_l = (float*)((char*)g_part + (size_t)NBLK * 16);
    float* ws_c = ws_l + BF;

    hipMemsetAsync(g_tred, 0, (size_t)BF * O_NUM * 4, stream);                    // capture-safe
    mfbl_k1<<<NBLK, NTHR, 0, stream>>>(loc, conf, anchors, targets, g_tred, g_part);
    mfbl_k2<<<BF, 64, 0, stream>>>(loc, conf, anchors, targets, g_tred, g_part, ws_l, ws_c);
    mfbl_k3<<<1, 256, 0, stream>>>(ws_l, ws_c, out, BF);
}

// Round 7
// 100.888 us; speedup vs baseline: 1.1708x; 1.1708x over previous
//
#include <hip/hip_runtime.h>
#include <math.h>

#define A_NUM 8732
#define O_NUM 32
#define NEGPOS 3
#define NTHR 256
#define NWAVE 4
#define ASPLIT 16
#define APB 546                        // ceil(8732/16); 16*546 = 8736
#define NITER 69                       // ceil(546 / (NWAVE * 2))
#define JMAX 3                         // ceil(546 / 256)
#define LOGEPS_F (-27.631021115928547f)

__device__ __forceinline__ unsigned int iou_hi(float tx1, float ty1, float tx2, float ty2, float ta,
                                               float px1, float py1, float px2, float py2, float ap) {
    float w = __saturatef(fminf(tx2, px2) - fmaxf(tx1, px1));
    float h = __saturatef(fminf(ty2, py2) - fmaxf(ty1, py1));
    float inter = w * h;
    float uni = (ta + ap) - inter;
    float iou = inter * __builtin_amdgcn_rcpf(uni);
    return __float_as_uint(iou) & 0xFFFFC000u;
}

__device__ __forceinline__ float sl1_sum(float4 t, float4 pr, float4 ld) {
    float gx = ((t.x + t.z) * 0.5f - pr.x) / (0.1f * pr.z);
    float gy = ((t.y + t.w) * 0.5f - pr.y) / (0.1f * pr.w);
    float gw = logf((t.z - t.x) / pr.z) / 0.2f;
    float gh = logf((t.w - t.y) / pr.w) / 0.2f;
    float d0 = ld.x - gx, d1 = ld.y - gy, d2 = ld.z - gw, d3 = ld.w - gh;
    float a0 = fabsf(d0), a1 = fabsf(d1), a2 = fabsf(d2), a3 = fabsf(d3);
    float s0 = (a0 < 1.0f) ? 0.5f * d0 * d0 : a0 - 0.5f;
    float s1 = (a1 < 1.0f) ? 0.5f * d1 * d1 : a1 - 0.5f;
    float s2 = (a2 < 1.0f) ? 0.5f * d2 * d2 : a2 - 0.5f;
    float s3 = (a3 < 1.0f) ? 0.5f * d3 * d3 : a3 - 0.5f;
    return s0 + s1 + s2 + s3;
}

__device__ __forceinline__ float bce_pos(int pred, float tgt) {
    float logp   = (pred == 0) ? LOGEPS_F : 0.0f;
    float log1mp = (pred == 1) ? LOGEPS_F : 0.0f;
    return -(tgt * logp + (1.0f - tgt) * log1mp);
}

// wave-wide max within each 32-lane half via DPP (pure VALU, no LDS pipe).
// Result valid in lane 31 (half 0) and lane 63 (half 1).
__device__ __forceinline__ int half_max_dpp(int k) {
    k = max(k, __builtin_amdgcn_update_dpp(k, k, 0x111, 0xf, 0xf, false)); // row_shr:1
    k = max(k, __builtin_amdgcn_update_dpp(k, k, 0x112, 0xf, 0xf, false)); // row_shr:2
    k = max(k, __builtin_amdgcn_update_dpp(k, k, 0x114, 0xf, 0xf, false)); // row_shr:4
    k = max(k, __builtin_amdgcn_update_dpp(k, k, 0x118, 0xf, 0xf, false)); // row_shr:8
    k = max(k, __builtin_amdgcn_update_dpp(k, k, 0x142, 0xf, 0xf, false)); // row_bcast:15
    return k;
}

// K1: grid = BF*ASPLIT blocks of 256 threads (4 waves).
// Wave-iteration = 2 anchors x 32 truths; truth lives in the lane's VGPRs.
__global__ __launch_bounds__(NTHR, 6) void mfbl_k1(
    const float* __restrict__ loc_data, const float* __restrict__ conf_data,
    const float* __restrict__ anchors, const float* __restrict__ targets,
    unsigned int* __restrict__ g_tred, float4* __restrict__ g_part)
{
    const int bid = blockIdx.x;
    const int frame = bid >> 4;
    const int split = bid & 15;
    const int a_lo = split * APB;
    const int a_hi = min(a_lo + APB, A_NUM);
    const int nA = a_hi - a_lo;                 // 546 (542 for last split)
    const int tid = threadIdx.x;
    const int lane = tid & 63;
    const int wid  = tid >> 6;
    const int h = lane >> 5;                    // which anchor of the pair
    const int o = lane & 31;                    // my truth

    __shared__ float4 s_pf[APB];                // point-form anchor corners
    __shared__ float  s_pap[APB];               // anchor area
    __shared__ unsigned int s_keyW[APB];        // per-anchor best (iou_hi | 31-o)
    __shared__ float4 s_tc[O_NUM];
    __shared__ float  s_ta[O_NUM], s_lab[O_NUM];
    __shared__ unsigned int s_tred[O_NUM][NWAVE];
    __shared__ float s_r[4][NWAVE];

    // prologue: stage truths + point-form anchors slice into LDS
    if (tid < O_NUM) {
        const float* t = targets + ((size_t)frame * O_NUM + tid) * 5;
        float x1 = t[0], y1 = t[1], x2 = t[2], y2 = t[3];
        s_tc[tid] = make_float4(x1, y1, x2, y2);
        s_ta[tid] = (x2 - x1) * (y2 - y1);
        s_lab[tid] = t[4];
    }
    for (int k = tid; k < nA; k += NTHR) {
        float4 pr = *(const float4*)(anchors + (size_t)(a_lo + k) * 4);
        float hw = pr.z * 0.5f, hh = pr.w * 0.5f;
        float4 pf = make_float4(pr.x - hw, pr.y - hh, pr.x + hw, pr.y + hh);
        s_pf[k] = pf;
        s_pap[k] = (pf.z - pf.x) * (pf.w - pf.y);
    }
    __syncthreads();

    // prefetch pass-2 conf loads so HBM latency hides under the pair loop
    float2 cd[JMAX];
#pragma unroll
    for (int j = 0; j < JMAX; ++j) {
        int k = tid + j * NTHR;
        if (k < nA) cd[j] = *(const float2*)(conf_data + ((size_t)frame * A_NUM + a_lo + k) * 2);
    }

    // my truth in registers (broadcast LDS read, once)
    const float4 tc = s_tc[o];
    const float  ta = s_ta[o];
    const unsigned int oc = (unsigned int)(31 - o);

    // ---------- hot loop ----------
    unsigned int tb = 0u;
    int idx = wid * 2 + h;                      // block-local anchor index, +8/iter
    for (int i = 0; i < NITER; ++i, idx += 8) {
        int ic = min(idx, nA - 1);              // clamped dup (uniform per half)
        float4 pf = s_pf[ic];
        float ap  = s_pap[ic];
        unsigned int hi = iou_hi(tc.x, tc.y, tc.z, tc.w, ta, pf.x, pf.y, pf.z, pf.w, ap);
        // per-truth running best (lane-local; dup's smaller aT can never win)
        tb = max(tb, hi | (16383u - (unsigned int)(a_lo + idx)));
        // per-anchor best across my half's 32 truths
        int k = half_max_dpp((int)(hi | oc));
        if ((lane & 31) == 31) s_keyW[ic] = (unsigned int)k;
    }

    // per-truth: combine the two halves, then across the block's waves
    tb = max(tb, (unsigned int)__shfl_xor((int)tb, 32));
    if (lane < O_NUM) s_tred[o][wid] = tb;
    __syncthreads();
    if (tid < O_NUM) {
        unsigned int k = s_tred[tid][0];
        for (int w = 1; w < NWAVE; ++w) k = max(k, s_tred[tid][w]);
        atomicMax(&g_tred[(size_t)frame * O_NUM + tid], k);    // commutative -> deterministic
    }

    // ---------- pass 2: unforced contributions ----------
    float l_sum = 0.0f, cpos = 0.0f, np_cnt = 0.0f, m_cnt = 0.0f;
#pragma unroll
    for (int j = 0; j < JMAX; ++j) {
        int k = tid + j * NTHR;
        if (k < nA) {
            unsigned int key = s_keyW[k];
            int bo = 31 - (int)(key & 31u);
            unsigned int hi = key & 0xFFFFC000u;
            int a = a_lo + k;
            int pred = (cd[j].y > cd[j].x) ? 1 : 0;
            int cv = (hi >= 0x3F000000u) ? (int)s_lab[bo] + 1 : 0;
            if (cv > 0) {
                np_cnt += 1.0f;
                float4 pr = *(const float4*)(anchors + (size_t)a * 4);
                float4 ld = *(const float4*)(loc_data + ((size_t)frame * A_NUM + a) * 4);
                l_sum += sl1_sum(s_tc[bo], pr, ld);
                cpos += bce_pos(pred, (float)cv);
            } else {
                m_cnt += (float)pred;     // negative with lc > log2 <=> pred==1
            }
        }
    }
    for (int s = 32; s > 0; s >>= 1) {
        l_sum  += __shfl_down(l_sum, s);
        cpos   += __shfl_down(cpos, s);
        np_cnt += __shfl_down(np_cnt, s);
        m_cnt  += __shfl_down(m_cnt, s);
    }
    if (lane == 0) { s_r[0][wid] = l_sum; s_r[1][wid] = cpos; s_r[2][wid] = np_cnt; s_r[3][wid] = m_cnt; }
    __syncthreads();
    if (tid == 0) {
        float L = 0, C = 0, NP = 0, M = 0;
        for (int w = 0; w < NWAVE; ++w) { L += s_r[0][w]; C += s_r[1][w]; NP += s_r[2][w]; M += s_r[3][w]; }
        g_part[bid] = make_float4(L, C, NP, M);
    }
}

// K2: grid = BF blocks x 64 threads. Forced-match corrections + finalize.
__global__ __launch_bounds__(64) void mfbl_k2(
    const float* __restrict__ loc_data, const float* __restrict__ conf_data,
    const float* __restrict__ anchors, const float* __restrict__ targets,
    const unsigned int* __restrict__ g_tred, const float4* __restrict__ g_part,
    float* __restrict__ ws_l, float* __restrict__ ws_c)
{
    const int frame = blockIdx.x;
    const int tid = threadIdx.x;

    __shared__ float4 s_tc[O_NUM];
    __shared__ float s_ta[O_NUM], s_lab[O_NUM];
    __shared__ int s_bp[O_NUM];

    if (tid < O_NUM) {
        const float* t = targets + ((size_t)frame * O_NUM + tid) * 5;
        float x1 = t[0], y1 = t[1], x2 = t[2], y2 = t[3];
        s_tc[tid] = make_float4(x1, y1, x2, y2);
        s_ta[tid] = (x2 - x1) * (y2 - y1);
        s_lab[tid] = t[4];
        unsigned int k = g_tred[(size_t)frame * O_NUM + tid];
        s_bp[tid] = 16383 - (int)(k & 16383u);
    }
    __syncthreads();

    float dL = 0.0f, dC = 0.0f, dNP = 0.0f, dM = 0.0f;
    if (tid < O_NUM) {
        int a = s_bp[tid];
        bool owner = true;                       // last truth writing this anchor wins
        for (int o2 = tid + 1; o2 < O_NUM; ++o2)
            if (s_bp[o2] == a) owner = false;
        if (owner) {
            float4 pr = *(const float4*)(anchors + (size_t)a * 4);
            float hw = pr.z * 0.5f, hh = pr.w * 0.5f;
            float px1 = pr.x - hw, py1 = pr.y - hh;
            float px2 = pr.x + hw, py2 = pr.y + hh;
            float apn = (px2 - px1) * (py2 - py1);
            unsigned int bk = 0u;                // recompute unforced best truth
            for (int o2 = 0; o2 < O_NUM; ++o2) {
                float4 t = s_tc[o2];
                unsigned int hi = iou_hi(t.x, t.y, t.z, t.w, s_ta[o2], px1, py1, px2, py2, apn);
                bk = max(bk, hi | (unsigned int)(31 - o2));
            }
            int old_o = 31 - (int)(bk & 31u);
            unsigned int old_hi = bk & 0xFFFFC000u;
            int old_cv = (old_hi >= 0x3F000000u) ? (int)s_lab[old_o] + 1 : 0;
            const float2 cdv = *(const float2*)(conf_data + ((size_t)frame * A_NUM + a) * 2);
            int pred = (cdv.y > cdv.x) ? 1 : 0;
            float4 ld = *(const float4*)(loc_data + ((size_t)frame * A_NUM + a) * 4);
            int new_cv = (int)s_lab[tid] + 1;
            dL = sl1_sum(s_tc[tid], pr, ld);
            dC = bce_pos(pred, (float)new_cv);
            dNP = 1.0f;
            if (old_cv > 0) {
                dL -= sl1_sum(s_tc[old_o], pr, ld);
                dC -= bce_pos(pred, (float)old_cv);
                dNP -= 1.0f;
            } else {
                dM -= (float)pred;
            }
        }
    }
    for (int s = 32; s > 0; s >>= 1) {
        dL += __shfl_down(dL, s);
        dC += __shfl_down(dC, s);
        dNP += __shfl_down(dNP, s);
        dM += __shfl_down(dM, s);
    }
    if (tid == 0) {
        float L = 0, C = 0, NP = 0, M = 0;
        for (int s = 0; s < ASPLIT; ++s) {
            float4 p = g_part[frame * ASPLIT + s];
            L += p.x; C += p.y; NP += p.z; M += p.w;
        }
        L += dL; C += dC; NP += dNP; M += dM;
        int np = (int)NP, m = (int)M;
        int num_neg = min(NEGPOS * np, A_NUM - 1);
        int nsel = min(num_neg, m);
        ws_l[frame] = L;
        ws_c[frame] = C + 27.631021115928547f * (float)nsel;
    }
}

__global__ void mfbl_k3(const float* __restrict__ ws_l, const float* __restrict__ ws_c,
                        float* __restrict__ out, int n) {
    int tid = threadIdx.x;
    float a = (tid < n) ? ws_l[tid] : 0.0f;
    float b = (tid < n) ? ws_c[tid] : 0.0f;
    for (int s = 32; s > 0; s >>= 1) {
        a += __shfl_down(a, s);
        b += __shfl_down(b, s);
    }
    __shared__ float sa[4], sb[4];
    int lane = tid & 63, wid = tid >> 6;
    if (lane == 0) { sa[wid] = a; sb[wid] = b; }
    __syncthreads();
    if (tid == 0) {
        float A = 0.0f, B = 0.0f;
        for (int w = 0; w < 4; ++w) { A += sa[w]; B += sb[w]; }
        out[0] = A;
        out[1] = B;
    }
}

extern "C" void kernel_launch(void* const* d_in, const int* in_sizes, int n_in,
                              void* d_out, int out_size, void* d_ws, size_t ws_size,
                              hipStream_t stream) {
    const float* loc     = (const float*)d_in[0];
    const float* conf    = (const float*)d_in[1];
    const float* anchors = (const float*)d_in[2];
    const float* targets = (const float*)d_in[3];
    float* out = (float*)d_out;
    (void)ws_size;

    const int BF = in_sizes[3] / (O_NUM * 5);   // 256 frames
    const int NBLK = BF * ASPLIT;

    unsigned int* g_tred = (unsigned int*)d_ws;                                   // BF*32 u32
    float4* g_part = (float4*)((char*)d_ws + (size_t)BF * O_NUM * 4);             // NBLK float4
    float* ws_l = (float*)((char*)g_part + (size_t)NBLK * 16);
    float* ws_c = ws_l + BF;

    hipMemsetAsync(g_tred, 0, (size_t)BF * O_NUM * 4, stream);                    // capture-safe
    mfbl_k1<<<NBLK, NTHR, 0, stream>>>(loc, conf, anchors, targets, g_tred, g_part);
    mfbl_k2<<<BF, 64, 0, stream>>>(loc, conf, anchors, targets, g_tred, g_part, ws_l, ws_c);
    mfbl_k3<<<1, 256, 0, stream>>>(ws_l, ws_c, out, BF);
}

// Round 8
// 80.813 us; speedup vs baseline: 1.4617x; 1.2484x over previous
//
#include <hip/hip_runtime.h>
#include <math.h>

#define A_NUM 8732
#define O_NUM 32
#define NEGPOS 3
#define NTHR 256
#define NWAVE 4
#define ASPLIT 12
#define APB 728                        // ceil(8732/12); 12*728 = 8736
#define K_ANCH 3                       // 3*256 = 768 >= 728 anchors/block
#define LOGEPS_F (-27.631021115928547f)

__device__ __forceinline__ unsigned int rotu(unsigned int v) {
    // row_ror:1 (0x121): rotate by 1 within each 16-lane row
    return (unsigned int)__builtin_amdgcn_update_dpp((int)v, (int)v, 0x121, 0xf, 0xf, false);
}
__device__ __forceinline__ float rotf(float v) {
    return __int_as_float((int)rotu((unsigned int)__float_as_int(v)));
}

// top-18 bits of IoU as a uint (IoU >= 0 so uint order == float order)
__device__ __forceinline__ unsigned int iou_hi(float tx1, float ty1, float tx2, float ty2, float ta,
                                               float px1, float py1, float px2, float py2, float ap) {
    float w = __saturatef(fminf(tx2, px2) - fmaxf(tx1, px1));
    float h = __saturatef(fminf(ty2, py2) - fmaxf(ty1, py1));
    float inter = w * h;
    float uni = (ta + ap) - inter;
    float iou = inter * __builtin_amdgcn_rcpf(uni);
    return __float_as_uint(iou) & 0xFFFFC000u;
}

__device__ __forceinline__ float sl1_sum(float4 t, float4 pr, float4 ld) {
    float gx = ((t.x + t.z) * 0.5f - pr.x) / (0.1f * pr.z);
    float gy = ((t.y + t.w) * 0.5f - pr.y) / (0.1f * pr.w);
    float gw = logf((t.z - t.x) / pr.z) / 0.2f;
    float gh = logf((t.w - t.y) / pr.w) / 0.2f;
    float d0 = ld.x - gx, d1 = ld.y - gy, d2 = ld.z - gw, d3 = ld.w - gh;
    float a0 = fabsf(d0), a1 = fabsf(d1), a2 = fabsf(d2), a3 = fabsf(d3);
    float s0 = (a0 < 1.0f) ? 0.5f * d0 * d0 : a0 - 0.5f;
    float s1 = (a1 < 1.0f) ? 0.5f * d1 * d1 : a1 - 0.5f;
    float s2 = (a2 < 1.0f) ? 0.5f * d2 * d2 : a2 - 0.5f;
    float s3 = (a3 < 1.0f) ? 0.5f * d3 * d3 : a3 - 0.5f;
    return s0 + s1 + s2 + s3;
}

__device__ __forceinline__ float bce_pos(int pred, float tgt) {
    float logp   = (pred == 0) ? LOGEPS_F : 0.0f;
    float log1mp = (pred == 1) ? LOGEPS_F : 0.0f;
    return -(tgt * logp + (1.0f - tgt) * log1mp);
}

// K1: grid = (ASPLIT, BF) blocks of 256 threads (4 waves).
// Anchors pinned in lane VGPRs (K_ANCH each); truths rotate through lanes via DPP.
// Hot loop touches no memory at all.
__global__ __launch_bounds__(NTHR) void mfbl_k1(
    const float* __restrict__ loc_data, const float* __restrict__ conf_data,
    const float* __restrict__ anchors, const float* __restrict__ targets,
    unsigned int* __restrict__ g_tred, float4* __restrict__ g_part)
{
    const int split = blockIdx.x;
    const int frame = blockIdx.y;
    const int a_lo = split * APB;
    const int nA = min(a_lo + APB, A_NUM) - a_lo;   // 728 (724 for last split)
    const int tid = threadIdx.x;
    const int lane = tid & 63;
    const int wid  = tid >> 6;
    const int r = lane >> 4;                         // row 0..3
    const int i = lane & 15;                         // in-row pos

    __shared__ float4 s_tc[O_NUM];
    __shared__ float  s_lab[O_NUM];
    __shared__ unsigned int s_tred[O_NUM][NWAVE];
    __shared__ float s_r[4][NWAVE];

    if (tid < O_NUM) {
        const float* t = targets + ((size_t)frame * O_NUM + tid) * 5;
        s_tc[tid] = make_float4(t[0], t[1], t[2], t[3]);
        s_lab[tid] = t[4];
    }

    // pin K_ANCH anchors per lane in registers (clamped dup loads for overflow
    // lanes; their per-truth keys carry a strictly smaller aT so they never win)
    float px1[K_ANCH], py1[K_ANCH], px2[K_ANCH], py2[K_ANCH], ap[K_ANCH];
    unsigned int bestA[K_ANCH], aT[K_ANCH];
    float2 cd[K_ANCH];
#pragma unroll
    for (int k = 0; k < K_ANCH; ++k) {
        int idx = tid + k * NTHR;
        int ic = min(idx, nA - 1);
        float4 pr = *(const float4*)(anchors + (size_t)(a_lo + ic) * 4);
        float hw = pr.z * 0.5f, hh = pr.w * 0.5f;
        px1[k] = pr.x - hw; py1[k] = pr.y - hh;
        px2[k] = pr.x + hw; py2[k] = pr.y + hh;
        ap[k] = (px2[k] - px1[k]) * (py2[k] - py1[k]);
        bestA[k] = 0u;
        aT[k] = 16383u - (unsigned int)(a_lo + idx);
        cd[k] = make_float2(0.0f, 0.0f);
        if (idx < nA)   // prefetch pass-2 conf so HBM latency hides under hot loop
            cd[k] = *(const float2*)(conf_data + ((size_t)frame * A_NUM + a_lo + idx) * 2);
    }
    __syncthreads();

    // ---------- hot loop: 2 phases x 16 systolic rotation steps ----------
    unsigned int tbp[2];
    for (int p = 0; p < 2; ++p) {
        const int t0 = (((r + p) & 1) << 4) | i;    // my starting truth
        float4 tc = s_tc[t0];
        float ta = (tc.z - tc.x) * (tc.w - tc.y);
        unsigned int oc = (unsigned int)(31 - t0);
        unsigned int tb = 0u;
#pragma unroll
        for (int s = 0; s < 16; ++s) {
#pragma unroll
            for (int k = 0; k < K_ANCH; ++k) {
                unsigned int hi = iou_hi(tc.x, tc.y, tc.z, tc.w, ta,
                                         px1[k], py1[k], px2[k], py2[k], ap[k]);
                bestA[k] = max(bestA[k], hi | oc);
                tb = max(tb, hi | aT[k]);
            }
            // rotate the truth (and its running best) to the next lane
            tc.x = rotf(tc.x); tc.y = rotf(tc.y);
            tc.z = rotf(tc.z); tc.w = rotf(tc.w);
            ta = rotf(ta); oc = rotu(oc); tb = rotu(tb);
        }
        tbp[p] = tb;   // 16 rotations = identity: tb is home
    }

    // combine per-truth partials: 4 copies (2 rows x 2 phases) per truth.
    unsigned int v = max(tbp[0], (unsigned int)__shfl_xor((int)tbp[1], 16));
    v = max(v, (unsigned int)__shfl_xor((int)v, 32));
    if (lane < O_NUM) s_tred[lane][wid] = v;        // lane < 32 holds truth 'lane'
    __syncthreads();
    if (tid < O_NUM) {
        unsigned int k = s_tred[tid][0];
        for (int w = 1; w < NWAVE; ++w) k = max(k, s_tred[tid][w]);
        atomicMax(&g_tred[(size_t)frame * O_NUM + tid], k);   // commutative -> deterministic
    }

    // ---------- pass 2: unforced contributions (anchors still in regs) ----------
    float l_sum = 0.0f, cpos = 0.0f, np_cnt = 0.0f, m_cnt = 0.0f;
#pragma unroll
    for (int k = 0; k < K_ANCH; ++k) {
        int idx = tid + k * NTHR;
        if (idx < nA) {
            unsigned int key = bestA[k];
            int bo = 31 - (int)(key & 31u);
            unsigned int hi = key & 0xFFFFC000u;
            int a = a_lo + idx;
            int pred = (cd[k].y > cd[k].x) ? 1 : 0;
            int cv = (hi >= 0x3F000000u) ? (int)s_lab[bo] + 1 : 0;
            if (cv > 0) {
                np_cnt += 1.0f;
                float4 pr = *(const float4*)(anchors + (size_t)a * 4);
                float4 ld = *(const float4*)(loc_data + ((size_t)frame * A_NUM + a) * 4);
                l_sum += sl1_sum(s_tc[bo], pr, ld);
                cpos += bce_pos(pred, (float)cv);
            } else {
                m_cnt += (float)pred;     // negative with lc > log2 <=> pred==1
            }
        }
    }
    for (int s = 32; s > 0; s >>= 1) {
        l_sum  += __shfl_down(l_sum, s);
        cpos   += __shfl_down(cpos, s);
        np_cnt += __shfl_down(np_cnt, s);
        m_cnt  += __shfl_down(m_cnt, s);
    }
    if (lane == 0) { s_r[0][wid] = l_sum; s_r[1][wid] = cpos; s_r[2][wid] = np_cnt; s_r[3][wid] = m_cnt; }
    __syncthreads();
    if (tid == 0) {
        float L = 0, C = 0, NP = 0, M = 0;
        for (int w = 0; w < NWAVE; ++w) { L += s_r[0][w]; C += s_r[1][w]; NP += s_r[2][w]; M += s_r[3][w]; }
        g_part[frame * ASPLIT + split] = make_float4(L, C, NP, M);
    }
}

// K2: grid = BF blocks x 64 threads. Forced-match corrections + finalize.
__global__ __launch_bounds__(64) void mfbl_k2(
    const float* __restrict__ loc_data, const float* __restrict__ conf_data,
    const float* __restrict__ anchors, const float* __restrict__ targets,
    const unsigned int* __restrict__ g_tred, const float4* __restrict__ g_part,
    float* __restrict__ ws_l, float* __restrict__ ws_c)
{
    const int frame = blockIdx.x;
    const int tid = threadIdx.x;

    __shared__ float4 s_tc[O_NUM];
    __shared__ float s_ta[O_NUM], s_lab[O_NUM];
    __shared__ int s_bp[O_NUM];

    if (tid < O_NUM) {
        const float* t = targets + ((size_t)frame * O_NUM + tid) * 5;
        float x1 = t[0], y1 = t[1], x2 = t[2], y2 = t[3];
        s_tc[tid] = make_float4(x1, y1, x2, y2);
        s_ta[tid] = (x2 - x1) * (y2 - y1);
        s_lab[tid] = t[4];
        unsigned int k = g_tred[(size_t)frame * O_NUM + tid];
        s_bp[tid] = 16383 - (int)(k & 16383u);
    }
    __syncthreads();

    float dL = 0.0f, dC = 0.0f, dNP = 0.0f, dM = 0.0f;
    if (tid < O_NUM) {
        int a = s_bp[tid];
        bool owner = true;                       // last truth writing this anchor wins
        for (int o2 = tid + 1; o2 < O_NUM; ++o2)
            if (s_bp[o2] == a) owner = false;
        if (owner) {
            float4 pr = *(const float4*)(anchors + (size_t)a * 4);
            float hw = pr.z * 0.5f, hh = pr.w * 0.5f;
            float px1 = pr.x - hw, py1 = pr.y - hh;
            float px2 = pr.x + hw, py2 = pr.y + hh;
            float apn = (px2 - px1) * (py2 - py1);
            unsigned int bk = 0u;                // recompute unforced best truth
            for (int o2 = 0; o2 < O_NUM; ++o2) {
                float4 t = s_tc[o2];
                unsigned int hi = iou_hi(t.x, t.y, t.z, t.w, s_ta[o2], px1, py1, px2, py2, apn);
                bk = max(bk, hi | (unsigned int)(31 - o2));
            }
            int old_o = 31 - (int)(bk & 31u);
            unsigned int old_hi = bk & 0xFFFFC000u;
            int old_cv = (old_hi >= 0x3F000000u) ? (int)s_lab[old_o] + 1 : 0;
            const float2 cdv = *(const float2*)(conf_data + ((size_t)frame * A_NUM + a) * 2);
            int pred = (cdv.y > cdv.x) ? 1 : 0;
            float4 ld = *(const float4*)(loc_data + ((size_t)frame * A_NUM + a) * 4);
            int new_cv = (int)s_lab[tid] + 1;
            dL = sl1_sum(s_tc[tid], pr, ld);
            dC = bce_pos(pred, (float)new_cv);
            dNP = 1.0f;
            if (old_cv > 0) {
                dL -= sl1_sum(s_tc[old_o], pr, ld);
                dC -= bce_pos(pred, (float)old_cv);
                dNP -= 1.0f;
            } else {
                dM -= (float)pred;
            }
        }
    }
    for (int s = 32; s > 0; s >>= 1) {
        dL += __shfl_down(dL, s);
        dC += __shfl_down(dC, s);
        dNP += __shfl_down(dNP, s);
        dM += __shfl_down(dM, s);
    }
    if (tid == 0) {
        float L = 0, C = 0, NP = 0, M = 0;
        for (int s = 0; s < ASPLIT; ++s) {
            float4 p = g_part[frame * ASPLIT + s];
            L += p.x; C += p.y; NP += p.z; M += p.w;
        }
        L += dL; C += dC; NP += dNP; M += dM;
        int np = (int)NP, m = (int)M;
        int num_neg = min(NEGPOS * np, A_NUM - 1);
        int nsel = min(num_neg, m);
        ws_l[frame] = L;
        ws_c[frame] = C + 27.631021115928547f * (float)nsel;
    }
}

__global__ void mfbl_k3(const float* __restrict__ ws_l, const float* __restrict__ ws_c,
                        float* __restrict__ out, int n) {
    int tid = threadIdx.x;
    float a = (tid < n) ? ws_l[tid] : 0.0f;
    float b = (tid < n) ? ws_c[tid] : 0.0f;
    for (int s = 32; s > 0; s >>= 1) {
        a += __shfl_down(a, s);
        b += __shfl_down(b, s);
    }
    __shared__ float sa[4], sb[4];
    int lane = tid & 63, wid = tid >> 6;
    if (lane == 0) { sa[wid] = a; sb[wid] = b; }
    __syncthreads();
    if (tid == 0) {
        float A = 0.0f, B = 0.0f;
        for (int w = 0; w < 4; ++w) { A += sa[w]; B += sb[w]; }
        out[0] = A;
        out[1] = B;
    }
}

extern "C" void kernel_launch(void* const* d_in, const int* in_sizes, int n_in,
                              void* d_out, int out_size, void* d_ws, size_t ws_size,
                              hipStream_t stream) {
    const float* loc     = (const float*)d_in[0];
    const float* conf    = (const float*)d_in[1];
    const float* anchors = (const float*)d_in[2];
    const float* targets = (const float*)d_in[3];
    float* out = (float*)d_out;
    (void)ws_size;

    const int BF = in_sizes[3] / (O_NUM * 5);   // 256 frames
    const int NBLK = BF * ASPLIT;

    unsigned int* g_tred = (unsigned int*)d_ws;                                   // BF*32 u32
    float4* g_part = (float4*)((char*)d_ws + (size_t)BF * O_NUM * 4);             // NBLK float4
    float* ws_l = (float*)((char*)g_part + (size_t)NBLK * 16);
    float* ws_c = ws_l + BF;

    hipMemsetAsync(g_tred, 0, (size_t)BF * O_NUM * 4, stream);                    // capture-safe
    mfbl_k1<<<dim3(ASPLIT, BF), NTHR, 0, stream>>>(loc, conf, anchors, targets, g_tred, g_part);
    mfbl_k2<<<BF, 64, 0, stream>>>(loc, conf, anchors, targets, g_tred, g_part, ws_l, ws_c);
    mfbl_k3<<<1, 256, 0, stream>>>(ws_l, ws_c, out, BF);
}